// Round 10
// baseline (16.888 us; speedup 1.0000x reference)
//
#include <hip/hip_runtime.h>
#include <math.h>

constexpr int NV  = 10;   // n_vars
constexpr int BLK = 256;  // 128 rows/block, 2 threads per row (wave-uniform halves)

#define CONST_AS __attribute__((address_space(4)))
__device__ __forceinline__ const CONST_AS float* cptr(const float* p) {
    return (const CONST_AS float*)(unsigned long long)p;
}

// dxdt half: outputs u in [5H, 5H+5). L streamed as 13 float4 per k (compile-time idx).
template<int H>
__device__ __forceinline__ void dxdt_half(const float4* __restrict__ L4,
                                          const float emb[5], const float xv[NV],
                                          float dx[5]) {
    #pragma unroll
    for (int k = 0; k < 5; ++k) {
        float zv[NV];
        const float ek = emb[k];
        #pragma unroll
        for (int v = 0; v < NV; ++v)
            zv[v] = (k == 0) ? xv[v] : ek * xv[v];
        #pragma unroll
        for (int j = 0; j < 13; ++j) {
            const int qi = 25 * k + 12 * H + j;        // compile-time
            const float4 q = L4[qi];
            #pragma unroll
            for (int cc = 0; cc < 4; ++cc) {
                const int ed    = 4 * qi + cc;          // global dword idx in L
                const int local = ed - (100 * k + 50 * H);
                if (local >= 0 && local < 50) {         // compile-time predicate
                    const int u = local / 10;           // 0..4 relative
                    const int v = local % 10;
                    const float qc = (cc == 0) ? q.x : (cc == 1) ? q.y
                                   : (cc == 2) ? q.z : q.w;
                    dx[u] = fmaf(qc, zv[v], dx[u]);
                }
            }
        }
    }
}

// attention for v in [5H,5H+5): attends {0,1,v} (v<2: {0,1})
template<int H>
__device__ __forceinline__ void attn_half(const float xv[NV], const float dx[5],
                                          float c, float ga, float res[5]) {
    const float x0 = xv[0], x1 = xv[1];
    #pragma unroll
    for (int i = 0; i < 5; ++i) {
        const int v = 5 * H + i;                        // compile-time
        const float s0 = xv[v] * x0 * c;
        const float s1 = xv[v] * x1 * c;
        float w;
        if (v < 2) {
            const float m = fmaxf(s0, s1);
            const float e0 = __expf(s0 - m), e1 = __expf(s1 - m);
            w = fmaf(e0, x0, e1 * x1) * __builtin_amdgcn_rcpf(e0 + e1);
        } else {
            const float sv = xv[v] * xv[v] * c;
            const float m = fmaxf(fmaxf(s0, s1), sv);
            const float e0 = __expf(s0 - m), e1 = __expf(s1 - m),
                        ev = __expf(sv - m);
            w = fmaf(e0, x0, fmaf(e1, x1, ev * xv[v]))
                * __builtin_amdgcn_rcpf(e0 + e1 + ev);
        }
        res[i] = fmaf(w, ga, dx[i]);
    }
}

// 64-VGPR cap -> 8 blocks/CU = 32 waves/CU (chip max)
__global__ __launch_bounds__(BLK, 8) void nxro_fused(
    const float* __restrict__ x,   // [B,10]
    const float* __restrict__ t,   // [B]
    const float* __restrict__ L,   // [5,10,10] = float4[125]
    const float* __restrict__ wq,  // [32]
    const float* __restrict__ wk,  // [32]
    const float* __restrict__ wv,  // [32]
    const float* __restrict__ wo,  // [32]
    const float* __restrict__ aw,  // [5]
    float* __restrict__ out,       // [B,10]
    int B)
{
    const int tid  = threadIdx.x;
    const int lane = tid & 63;
    const int rloc = tid & 127;          // row within block
    const int h    = tid >> 7;           // 0: outputs 0-4, 1: outputs 5-9 (wave-uniform)

    const long long row = (long long)blockIdx.x * 128 + rloc;
    const bool act = (row < (long long)B);
    const long long ri = act ? row : 0;

    // ---- issue per-row global loads FIRST ----
    const float tt = t[ri];
    float2 p[5];
    {
        const float2* xr = reinterpret_cast<const float2*>(x + ri * NV);
        #pragma unroll
        for (int i = 0; i < 5; ++i) p[i] = xr[i];
    }

    // ---- c,g while x/t in flight: lane-split dot + butterfly reduce ----
    float pa, pb;
    if (lane < 32) { pa = wq[lane];      pb = wk[lane];      }
    else           { pa = wv[lane - 32]; pb = wo[lane - 32]; }
    float dotv = pa * pb;
    #pragma unroll
    for (int m = 16; m >= 1; m >>= 1)
        dotv += __shfl_xor(dotv, m, 64);
    const float c = __shfl(dotv, 0, 64) * 0.17677669529663687f; // (wq.wk)/sqrt(32)
    const float g = __shfl(dotv, 32, 64);                        // wv.wo

    // ---- Fourier embedding (HW sin/cos take REVOLUTIONS; t in [0,1)) ----
    const float t2 = tt + tt;
    const float emb[5] = {
        1.f,
        __builtin_amdgcn_cosf(tt),
        __builtin_amdgcn_sinf(tt),
        __builtin_amdgcn_cosf(t2),
        __builtin_amdgcn_sinf(t2)
    };

    float xv[NV];
    #pragma unroll
    for (int i = 0; i < 5; ++i) { xv[2*i] = p[i].x; xv[2*i+1] = p[i].y; }

    // ---- alpha = sigmoid(emb . alpha_w); aw via scalar pipe ----
    const CONST_AS float* awc = cptr(aw);
    float zs = awc[0];
    zs = fmaf(emb[1], awc[1], zs);
    zs = fmaf(emb[2], awc[2], zs);
    zs = fmaf(emb[3], awc[3], zs);
    zs = fmaf(emb[4], awc[4], zs);
    const float ga = g * __builtin_amdgcn_rcpf(1.f + __expf(-zs));

    const float4* __restrict__ L4 = reinterpret_cast<const float4*>(L);
    float dx[5] = {0.f, 0.f, 0.f, 0.f, 0.f};
    float res[5];

    if (h == 0) {                         // wave-uniform branch
        dxdt_half<0>(L4, emb, xv, dx);
        attn_half<0>(xv, dx, c, ga, res);
        if (act) {
            float* op = out + row * NV;   // 8B aligned (40B rows)
            *reinterpret_cast<float2*>(op)     = make_float2(res[0], res[1]);
            *reinterpret_cast<float2*>(op + 2) = make_float2(res[2], res[3]);
            op[4] = res[4];
        }
    } else {
        dxdt_half<1>(L4, emb, xv, dx);
        attn_half<1>(xv, dx, c, ga, res);
        if (act) {
            float* op = out + row * NV + 5;
            op[0] = res[0];                               // offset 20B: 4B aligned
            *reinterpret_cast<float2*>(op + 1) = make_float2(res[1], res[2]); // 24B: 8B ok
            *reinterpret_cast<float2*>(op + 3) = make_float2(res[3], res[4]); // 32B: 8B ok
        }
    }
}

extern "C" void kernel_launch(void* const* d_in, const int* in_sizes, int n_in,
                              void* d_out, int out_size, void* d_ws, size_t ws_size,
                              hipStream_t stream) {
    const float* x  = (const float*)d_in[0];
    const float* t  = (const float*)d_in[1];
    const float* L  = (const float*)d_in[2];
    const float* wq = (const float*)d_in[3];
    const float* wk = (const float*)d_in[4];
    const float* wv = (const float*)d_in[5];
    const float* wo = (const float*)d_in[6];
    const float* aw = (const float*)d_in[7];
    float* out = (float*)d_out;
    const int B = in_sizes[1];  // t_years element count

    const int rowsPerBlk = 128;
    const int grid = (B + rowsPerBlk - 1) / rowsPerBlk;
    nxro_fused<<<grid, BLK, 0, stream>>>(x, t, L, wq, wk, wv, wo, aw, out, B);
}

// Round 11
// 13.060 us; speedup vs baseline: 1.2931x; 1.2931x over previous
//
#include <hip/hip_runtime.h>
#include <math.h>

constexpr int NV  = 10;   // n_vars
constexpr int BLK = 256;  // 128 rows/block, 2 threads per row (wave-uniform halves)

#define CONST_AS __attribute__((address_space(4)))
__device__ __forceinline__ const CONST_AS float* cptr(const float* p) {
    return (const CONST_AS float*)(unsigned long long)p;
}

// dxdt half: outputs u in [5H, 5H+5). L streamed as 13 float4 per k (compile-time idx).
template<int H>
__device__ __forceinline__ void dxdt_half(const float4* __restrict__ L4,
                                          const float emb[5], const float xv[NV],
                                          float dx[5]) {
    #pragma unroll
    for (int k = 0; k < 5; ++k) {
        float zv[NV];
        const float ek = emb[k];
        #pragma unroll
        for (int v = 0; v < NV; ++v)
            zv[v] = (k == 0) ? xv[v] : ek * xv[v];
        #pragma unroll
        for (int j = 0; j < 13; ++j) {
            const int qi = 25 * k + 12 * H + j;        // compile-time
            const float4 q = L4[qi];
            #pragma unroll
            for (int cc = 0; cc < 4; ++cc) {
                const int ed    = 4 * qi + cc;          // global dword idx in L
                const int local = ed - (100 * k + 50 * H);
                if (local >= 0 && local < 50) {         // compile-time predicate
                    const int u = local / 10;           // 0..4 relative
                    const int v = local % 10;
                    const float qc = (cc == 0) ? q.x : (cc == 1) ? q.y
                                   : (cc == 2) ? q.z : q.w;
                    dx[u] = fmaf(qc, zv[v], dx[u]);
                }
            }
        }
    }
}

// attention for v in [5H,5H+5): attends {0,1,v} (v<2: {0,1})
template<int H>
__device__ __forceinline__ void attn_half(const float xv[NV], const float dx[5],
                                          float c, float ga, float res[5]) {
    const float x0 = xv[0], x1 = xv[1];
    #pragma unroll
    for (int i = 0; i < 5; ++i) {
        const int v = 5 * H + i;                        // compile-time
        const float s0 = xv[v] * x0 * c;
        const float s1 = xv[v] * x1 * c;
        float w;
        if (v < 2) {
            const float m = fmaxf(s0, s1);
            const float e0 = __expf(s0 - m), e1 = __expf(s1 - m);
            w = fmaf(e0, x0, e1 * x1) * __builtin_amdgcn_rcpf(e0 + e1);
        } else {
            const float sv = xv[v] * xv[v] * c;
            const float m = fmaxf(fmaxf(s0, s1), sv);
            const float e0 = __expf(s0 - m), e1 = __expf(s1 - m),
                        ev = __expf(sv - m);
            w = fmaf(e0, x0, fmaf(e1, x1, ev * xv[v]))
                * __builtin_amdgcn_rcpf(e0 + e1 + ev);
        }
        res[i] = fmaf(w, ga, dx[i]);
    }
}

// 64-VGPR cap -> 8 blocks/CU = 32 waves/CU (chip max)
__global__ __launch_bounds__(BLK, 8) void nxro_fused(
    const float* __restrict__ x,   // [B,10]
    const float* __restrict__ t,   // [B]
    const float* __restrict__ L,   // [5,10,10] = float4[125]
    const float* __restrict__ wq,  // [32]
    const float* __restrict__ wk,  // [32]
    const float* __restrict__ wv,  // [32]
    const float* __restrict__ wo,  // [32]
    const float* __restrict__ aw,  // [5]
    float* __restrict__ out,       // [B,10]
    int B)
{
    const int tid  = threadIdx.x;
    const int lane = tid & 63;
    const int rloc = tid & 127;          // row within block
    const int h    = tid >> 7;           // 0: outputs 0-4, 1: outputs 5-9 (wave-uniform)

    const long long row = (long long)blockIdx.x * 128 + rloc;
    const bool act = (row < (long long)B);
    const long long ri = act ? row : 0;

    // ---- issue per-row global loads FIRST ----
    const float tt = t[ri];
    float2 p[5];
    {
        const float2* xr = reinterpret_cast<const float2*>(x + ri * NV);
        #pragma unroll
        for (int i = 0; i < 5; ++i) p[i] = xr[i];
    }

    // ---- c,g while x/t in flight: lane-split dot + butterfly reduce ----
    float pa, pb;
    if (lane < 32) { pa = wq[lane];      pb = wk[lane];      }
    else           { pa = wv[lane - 32]; pb = wo[lane - 32]; }
    float dotv = pa * pb;
    #pragma unroll
    for (int m = 16; m >= 1; m >>= 1)
        dotv += __shfl_xor(dotv, m, 64);
    const float c = __shfl(dotv, 0, 64) * 0.17677669529663687f; // (wq.wk)/sqrt(32)
    const float g = __shfl(dotv, 32, 64);                        // wv.wo

    // ---- Fourier embedding (HW sin/cos take REVOLUTIONS; t in [0,1)) ----
    const float t2 = tt + tt;
    const float emb[5] = {
        1.f,
        __builtin_amdgcn_cosf(tt),
        __builtin_amdgcn_sinf(tt),
        __builtin_amdgcn_cosf(t2),
        __builtin_amdgcn_sinf(t2)
    };

    float xv[NV];
    #pragma unroll
    for (int i = 0; i < 5; ++i) { xv[2*i] = p[i].x; xv[2*i+1] = p[i].y; }

    // ---- alpha = sigmoid(emb . alpha_w); aw via scalar pipe ----
    const CONST_AS float* awc = cptr(aw);
    float zs = awc[0];
    zs = fmaf(emb[1], awc[1], zs);
    zs = fmaf(emb[2], awc[2], zs);
    zs = fmaf(emb[3], awc[3], zs);
    zs = fmaf(emb[4], awc[4], zs);
    const float ga = g * __builtin_amdgcn_rcpf(1.f + __expf(-zs));

    const float4* __restrict__ L4 = reinterpret_cast<const float4*>(L);
    float dx[5] = {0.f, 0.f, 0.f, 0.f, 0.f};
    float res[5];

    if (h == 0) {                         // wave-uniform branch
        dxdt_half<0>(L4, emb, xv, dx);
        attn_half<0>(xv, dx, c, ga, res);
        if (act) {
            float* op = out + row * NV;   // 8B aligned (40B rows)
            *reinterpret_cast<float2*>(op)     = make_float2(res[0], res[1]);
            *reinterpret_cast<float2*>(op + 2) = make_float2(res[2], res[3]);
            op[4] = res[4];
        }
    } else {
        dxdt_half<1>(L4, emb, xv, dx);
        attn_half<1>(xv, dx, c, ga, res);
        if (act) {
            float* op = out + row * NV + 5;
            op[0] = res[0];                               // offset 20B: 4B aligned
            *reinterpret_cast<float2*>(op + 1) = make_float2(res[1], res[2]); // 24B: 8B ok
            *reinterpret_cast<float2*>(op + 3) = make_float2(res[3], res[4]); // 32B: 8B ok
        }
    }
}

extern "C" void kernel_launch(void* const* d_in, const int* in_sizes, int n_in,
                              void* d_out, int out_size, void* d_ws, size_t ws_size,
                              hipStream_t stream) {
    const float* x  = (const float*)d_in[0];
    const float* t  = (const float*)d_in[1];
    const float* L  = (const float*)d_in[2];
    const float* wq = (const float*)d_in[3];
    const float* wk = (const float*)d_in[4];
    const float* wv = (const float*)d_in[5];
    const float* wo = (const float*)d_in[6];
    const float* aw = (const float*)d_in[7];
    float* out = (float*)d_out;
    const int B = in_sizes[1];  // t_years element count

    const int rowsPerBlk = 128;
    const int grid = (B + rowsPerBlk - 1) / rowsPerBlk;
    nxro_fused<<<grid, BLK, 0, stream>>>(x, t, L, wq, wk, wv, wo, aw, out, B);
}